// Round 4
// baseline (414.085 us; speedup 1.0000x reference)
//
#include <hip/hip_runtime.h>
#include <math.h>

// Problem constants (from reference): D=256, DIN=512, F=16
#define DD 256
#define REPS 8   // replicated accumulators to reduce atomic same-address contention

// Workspace layout (float offsets)
#define OFF_SUMREP 0        // 2 inputs * REPS * 256 = 4096
#define OFF_H1P    4096     // 2 * 256 = 512   (pre-tanh partial sums, atomic target)
#define OFF_S1REP  4608     // 4096
#define OFF_H2P    8704     // 512
#define OFF_OREP   9216     // 4096
#define OFF_O      13312    // 512  (o1 then o2)
#define OFF_WTREP  13824    // REPS * 16 = 128
#define WS_FLOATS  13952

typedef float f32x4 __attribute__((ext_vector_type(4)));

__device__ __forceinline__ float sigmoidf_(float x) { return 1.0f / (1.0f + __expf(-x)); }
__device__ __forceinline__ float dot4(f32x4 a, f32x4 b) {
    return a.x * b.x + a.y * b.y + a.z * b.z + a.w * b.w;
}
__device__ __forceinline__ float wave_sum(float v) {
#pragma unroll
    for (int off = 32; off; off >>= 1) v += __shfl_xor(v, off, 64);
    return v;
}

// 8 L1-bypassing (sc0) dwordx4 loads + drain, as ONE asm block so the
// compiler cannot schedule consumers before the waitcnt.
#define LOAD8_SC0(v0,v1,v2,v3,v4,v5,v6,v7, p, S)                               \
    asm volatile(                                                              \
        "global_load_dwordx4 %0, %8, off sc0\n\t"                              \
        "global_load_dwordx4 %1, %9, off sc0\n\t"                              \
        "global_load_dwordx4 %2, %10, off sc0\n\t"                             \
        "global_load_dwordx4 %3, %11, off sc0\n\t"                             \
        "global_load_dwordx4 %4, %12, off sc0\n\t"                             \
        "global_load_dwordx4 %5, %13, off sc0\n\t"                             \
        "global_load_dwordx4 %6, %14, off sc0\n\t"                             \
        "global_load_dwordx4 %7, %15, off sc0\n\t"                             \
        "s_waitcnt vmcnt(0)"                                                   \
        : "=&v"(v0), "=&v"(v1), "=&v"(v2), "=&v"(v3),                          \
          "=&v"(v4), "=&v"(v5), "=&v"(v6), "=&v"(v7)                           \
        : "v"(p), "v"((p) + (S)), "v"((p) + 2*(S)), "v"((p) + 3*(S)),          \
          "v"((p) + 4*(S)), "v"((p) + 5*(S)), "v"((p) + 6*(S)), "v"((p) + 7*(S)))

__global__ void k_zero(float* __restrict__ ws) {
    int i = blockIdx.x * 256 + threadIdx.x;
    if (i < WS_FLOATS) ws[i] = 0.0f;
}

// Block-level f32x4 reduce of 4 waves + replicated atomic finish.
__device__ __forceinline__ void block_reduce_atomic(f32x4 acc, int t, float* dst_base) {
    __shared__ f32x4 lds[256];
    lds[t] = acc;
    __syncthreads();
    if (t < 64) {
        f32x4 s = lds[t] + lds[t + 64] + lds[t + 128] + lds[t + 192];
        float* dst = dst_base + t * 4;
        atomicAdd(dst + 0, s.x); atomicAdd(dst + 1, s.y);
        atomicAdd(dst + 2, s.z); atomicAdd(dst + 3, s.w);
    }
}

// Pass A: column sums. Grid = 2048 blocks; [0,1024)->x1, [1024,2048)->x2.
__global__ void __launch_bounds__(256, 4)
k_mean(const float* __restrict__ x1, const float* __restrict__ x2,
       int N1, int N2, float* __restrict__ ws) {
    int b = blockIdx.x, t = threadIdx.x;
    int inp = b >> 10;
    int bl = b & 1023;
    const f32x4* x = (const f32x4*)(inp ? x2 : x1);
    int N = inp ? N2 : N1;
    int chunk = (N + 1023) >> 10;
    int start = bl * chunk;
    int end = min(start + chunk, N);
    int lane = t & 63, w = t >> 6;
    f32x4 a0 = {0.f, 0.f, 0.f, 0.f}, a1 = a0;
    int r = start + w;
    for (; r + 28 < end; r += 32) {
        const f32x4* p = x + (size_t)r * 64 + lane;
        f32x4 v0, v1, v2, v3, v4, v5, v6, v7;
        LOAD8_SC0(v0, v1, v2, v3, v4, v5, v6, v7, p, 256);
        a0 += v0 + v2; a1 += v1 + v3;
        a0 += v4 + v6; a1 += v5 + v7;
    }
    for (; r < end; r += 4) a0 += x[(size_t)r * 64 + lane];
    a0 += a1;
    block_reduce_atomic(a0, t, ws + OFF_SUMREP + inp * (REPS * 256) + (bl & (REPS - 1)) * 256);
}

// hP[inp] += partial of (colsum/N) @ W0 over a 16-row slice of W0.
__global__ void k_hpart(const float* __restrict__ W0, float* __restrict__ ws,
                        int srcOff, int dstOff, int N1, int N2) {
    int inp = blockIdx.x >> 4, g = blockIdx.x & 15;
    int t = threadIdx.x;
    __shared__ float temp[16];
    if (t < 16) {
        const float* src = ws + srcOff + inp * (REPS * 256) + g * 16 + t;
        float s = 0.f;
#pragma unroll
        for (int r = 0; r < REPS; r++) s += src[r * 256];
        temp[t] = s * (1.0f / (float)(inp ? N2 : N1));
    }
    __syncthreads();
    float p = 0.f;
#pragma unroll
    for (int j = 0; j < 16; j++) p += temp[j] * W0[(g * 16 + j) * 256 + t];
    atomicAdd(ws + dstOff + inp * 256 + t, p);
}

// Pass B: s1 = sum_i sigmoid(x_i . h1) * x_i.
__global__ void __launch_bounds__(256, 4)
k_att1(const float* __restrict__ x1, const float* __restrict__ x2,
       int N1, int N2, float* __restrict__ ws) {
    int b = blockIdx.x, t = threadIdx.x;
    int inp = b >> 10;
    int bl = b & 1023;
    const f32x4* x = (const f32x4*)(inp ? x2 : x1);
    int N = inp ? N2 : N1;
    int chunk = (N + 1023) >> 10;
    int start = bl * chunk;
    int end = min(start + chunk, N);
    int lane = t & 63, w = t >> 6;
    f32x4 hp = ((const f32x4*)(ws + OFF_H1P + inp * 256))[lane];
    f32x4 h1 = {tanhf(hp.x), tanhf(hp.y), tanhf(hp.z), tanhf(hp.w)};
    f32x4 acc = {0.f, 0.f, 0.f, 0.f};
    int r = start + w;
    for (; r + 28 < end; r += 32) {
        const f32x4* p = x + (size_t)r * 64 + lane;
        f32x4 v0, v1, v2, v3, v4, v5, v6, v7;
        LOAD8_SC0(v0, v1, v2, v3, v4, v5, v6, v7, p, 256);
        float d[8];
        d[0] = dot4(v0, h1); d[1] = dot4(v1, h1); d[2] = dot4(v2, h1); d[3] = dot4(v3, h1);
        d[4] = dot4(v4, h1); d[5] = dot4(v5, h1); d[6] = dot4(v6, h1); d[7] = dot4(v7, h1);
#pragma unroll
        for (int off = 32; off; off >>= 1) {
#pragma unroll
            for (int u = 0; u < 8; u++) d[u] += __shfl_xor(d[u], off, 64);
        }
        acc += sigmoidf_(d[0]) * v0 + sigmoidf_(d[1]) * v1;
        acc += sigmoidf_(d[2]) * v2 + sigmoidf_(d[3]) * v3;
        acc += sigmoidf_(d[4]) * v4 + sigmoidf_(d[5]) * v5;
        acc += sigmoidf_(d[6]) * v6 + sigmoidf_(d[7]) * v7;
    }
    for (; r < end; r += 4) {
        f32x4 v = x[(size_t)r * 64 + lane];
        float d = wave_sum(dot4(v, h1));
        acc += sigmoidf_(d) * v;
    }
    block_reduce_atomic(acc, t, ws + OFF_S1REP + inp * (REPS * 256) + (bl & (REPS - 1)) * 256);
}

// Pass C: o = sum_i att1_i*att2_i*x_i, att2_i = sigmoid(att1_i * (x_i . h2)).
__global__ void __launch_bounds__(256, 4)
k_att2(const float* __restrict__ x1, const float* __restrict__ x2,
       int N1, int N2, float* __restrict__ ws) {
    int b = blockIdx.x, t = threadIdx.x;
    int inp = b >> 10;
    int bl = b & 1023;
    const f32x4* x = (const f32x4*)(inp ? x2 : x1);
    int N = inp ? N2 : N1;
    int chunk = (N + 1023) >> 10;
    int start = bl * chunk;
    int end = min(start + chunk, N);
    int lane = t & 63, w = t >> 6;
    f32x4 hp1 = ((const f32x4*)(ws + OFF_H1P + inp * 256))[lane];
    f32x4 hp2 = ((const f32x4*)(ws + OFF_H2P + inp * 256))[lane];
    f32x4 h1 = {tanhf(hp1.x), tanhf(hp1.y), tanhf(hp1.z), tanhf(hp1.w)};
    f32x4 h2 = {tanhf(hp2.x), tanhf(hp2.y), tanhf(hp2.z), tanhf(hp2.w)};
    f32x4 acc = {0.f, 0.f, 0.f, 0.f};
    int r = start + w;
    for (; r + 12 < end; r += 16) {
        const f32x4* p = x + (size_t)r * 64 + lane;
        f32x4 v0, v1, v2, v3;
        asm volatile(
            "global_load_dwordx4 %0, %4, off sc0\n\t"
            "global_load_dwordx4 %1, %5, off sc0\n\t"
            "global_load_dwordx4 %2, %6, off sc0\n\t"
            "global_load_dwordx4 %3, %7, off sc0\n\t"
            "s_waitcnt vmcnt(0)"
            : "=&v"(v0), "=&v"(v1), "=&v"(v2), "=&v"(v3)
            : "v"(p), "v"(p + 256), "v"(p + 512), "v"(p + 768));
        float d[4], e[4];
        d[0] = dot4(v0, h1); e[0] = dot4(v0, h2);
        d[1] = dot4(v1, h1); e[1] = dot4(v1, h2);
        d[2] = dot4(v2, h1); e[2] = dot4(v2, h2);
        d[3] = dot4(v3, h1); e[3] = dot4(v3, h2);
#pragma unroll
        for (int off = 32; off; off >>= 1) {
#pragma unroll
            for (int u = 0; u < 4; u++) {
                d[u] += __shfl_xor(d[u], off, 64);
                e[u] += __shfl_xor(e[u], off, 64);
            }
        }
        float a10 = sigmoidf_(d[0]), a11 = sigmoidf_(d[1]);
        float a12 = sigmoidf_(d[2]), a13 = sigmoidf_(d[3]);
        acc += (a10 * sigmoidf_(a10 * e[0])) * v0 + (a11 * sigmoidf_(a11 * e[1])) * v1;
        acc += (a12 * sigmoidf_(a12 * e[2])) * v2 + (a13 * sigmoidf_(a13 * e[3])) * v3;
    }
    for (; r < end; r += 4) {
        f32x4 v = x[(size_t)r * 64 + lane];
        float d = dot4(v, h1), e = dot4(v, h2);
#pragma unroll
        for (int off = 32; off; off >>= 1) {
            d += __shfl_xor(d, off, 64); e += __shfl_xor(e, off, 64);
        }
        float a1 = sigmoidf_(d);
        acc += (a1 * sigmoidf_(a1 * e)) * v;
    }
    block_reduce_atomic(acc, t, ws + OFF_OREP + inp * (REPS * 256) + (bl & (REPS - 1)) * 256);
}

// Combine o replicas -> o1[256], o2[256]
__global__ void k_comb(float* __restrict__ ws) {
    int t = threadIdx.x;           // 512 threads
    int inp = t >> 8, c = t & 255;
    float s = 0.f;
#pragma unroll
    for (int r = 0; r < REPS; r++) s += ws[OFF_OREP + inp * (REPS * 256) + r * 256 + c];
    ws[OFF_O + t] = s;
}

// w_term[f] = sum_{d,e} g1[d] W[f,d,e] g2[e], g=[o,o] duplication folded.
// 8192 rows (f,d) of 512 floats. 512 blocks x 16 rows; wave-per-row, 4 rows/wave.
__global__ void __launch_bounds__(256, 4)
k_ntn(const float* __restrict__ W, float* __restrict__ ws) {
    int b = blockIdx.x, t = threadIdx.x;
    int lane = t & 63, w = t >> 6;
    const float* o1 = ws + OFF_O;
    f32x4 o2f = ((const f32x4*)(ws + OFF_O + 256))[lane];
    int f = b >> 5;                 // 32 blocks per feature map
    int r0 = b * 16 + w;            // rows r0, r0+4, r0+8, r0+12
    const f32x4* q0 = (const f32x4*)W + (size_t)r0 * 128 + lane;
    f32x4 a0, c0, a1, c1, a2, c2, a3, c3;
    asm volatile(
        "global_load_dwordx4 %0, %8, off sc0\n\t"
        "global_load_dwordx4 %1, %9, off sc0\n\t"
        "global_load_dwordx4 %2, %10, off sc0\n\t"
        "global_load_dwordx4 %3, %11, off sc0\n\t"
        "global_load_dwordx4 %4, %12, off sc0\n\t"
        "global_load_dwordx4 %5, %13, off sc0\n\t"
        "global_load_dwordx4 %6, %14, off sc0\n\t"
        "global_load_dwordx4 %7, %15, off sc0\n\t"
        "s_waitcnt vmcnt(0)"
        : "=&v"(a0), "=&v"(c0), "=&v"(a1), "=&v"(c1),
          "=&v"(a2), "=&v"(c2), "=&v"(a3), "=&v"(c3)
        : "v"(q0), "v"(q0 + 64), "v"(q0 + 512), "v"(q0 + 576),
          "v"(q0 + 1024), "v"(q0 + 1088), "v"(q0 + 1536), "v"(q0 + 1600));
    float p0 = dot4(a0 + c0, o2f);
    float p1 = dot4(a1 + c1, o2f);
    float p2 = dot4(a2 + c2, o2f);
    float p3 = dot4(a3 + c3, o2f);
#pragma unroll
    for (int off = 32; off; off >>= 1) {
        p0 += __shfl_xor(p0, off, 64); p1 += __shfl_xor(p1, off, 64);
        p2 += __shfl_xor(p2, off, 64); p3 += __shfl_xor(p3, off, 64);
    }
    if (lane == 0) {
        float* dst = ws + OFF_WTREP + (b & (REPS - 1)) * 16 + f;
        int d = r0 & 511;
        atomicAdd(dst, o1[d & 255] * p0
                     + o1[(d + 4) & 255] * p1
                     + o1[(d + 8) & 255] * p2
                     + o1[(d + 12) & 255] * p3);
    }
}

// v_term + w_term + b -> sigmoid -> 4-layer MLP -> out[0]
__global__ void k_final(const float* __restrict__ V, const float* __restrict__ bb,
                        const float* __restrict__ P0, const float* __restrict__ P1,
                        const float* __restrict__ P2, const float* __restrict__ P3,
                        float* __restrict__ ws, float* __restrict__ out) {
    int t = threadIdx.x;           // 256 threads
    const float* o = ws + OFF_O;
    int f = t >> 4, j = t & 15;
    float p = 0.f;
    for (int k = j; k < 1024; k += 16) {
        float cv = (k < 512) ? o[k & 255] : o[256 + (k & 255)];
        p += cv * V[f * 1024 + k];
    }
    __shared__ float red[256];
    __shared__ float sv[16];
    red[t] = p;
    __syncthreads();
    if (t < 16) {
        float v = 0.f;
#pragma unroll
        for (int q = 0; q < 16; q++) v += red[t * 16 + q];
        float wt = 0.f;
#pragma unroll
        for (int r = 0; r < REPS; r++) wt += ws[OFF_WTREP + r * 16 + t];
        sv[t] = sigmoidf_(v + wt + bb[t]);
    }
    __syncthreads();
    if (t == 0) {
        float y0[8], y1[4], y2[2];
#pragma unroll
        for (int i = 0; i < 8; i++) {
            float s = 0.f;
            for (int k = 0; k < 16; k++) s += P0[i * 16 + k] * sv[k];
            y0[i] = sigmoidf_(s);
        }
#pragma unroll
        for (int i = 0; i < 4; i++) {
            float s = 0.f;
            for (int k = 0; k < 8; k++) s += P1[i * 8 + k] * y0[k];
            y1[i] = sigmoidf_(s);
        }
#pragma unroll
        for (int i = 0; i < 2; i++) {
            float s = 0.f;
            for (int k = 0; k < 4; k++) s += P2[i * 4 + k] * y1[k];
            y2[i] = sigmoidf_(s);
        }
        out[0] = sigmoidf_(P3[0] * y2[0] + P3[1] * y2[1]);
    }
}

extern "C" void kernel_launch(void* const* d_in, const int* in_sizes, int n_in,
                              void* d_out, int out_size, void* d_ws, size_t ws_size,
                              hipStream_t stream) {
    const float* x1 = (const float*)d_in[0];
    const float* x2 = (const float*)d_in[1];
    const float* W0 = (const float*)d_in[2];
    const float* V  = (const float*)d_in[3];
    const float* W  = (const float*)d_in[4];
    const float* b  = (const float*)d_in[5];
    const float* P0 = (const float*)d_in[6];
    const float* P1 = (const float*)d_in[7];
    const float* P2 = (const float*)d_in[8];
    const float* P3 = (const float*)d_in[9];
    float* ws  = (float*)d_ws;
    float* out = (float*)d_out;
    int N1 = in_sizes[0] / DD;   // 120000
    int N2 = in_sizes[1] / DD;   // 100000

    k_zero  <<<55,   256, 0, stream>>>(ws);
    k_mean  <<<2048, 256, 0, stream>>>(x1, x2, N1, N2, ws);
    k_hpart <<<32,   256, 0, stream>>>(W0, ws, OFF_SUMREP, OFF_H1P, N1, N2);
    k_att1  <<<2048, 256, 0, stream>>>(x1, x2, N1, N2, ws);
    k_hpart <<<32,   256, 0, stream>>>(W0, ws, OFF_S1REP, OFF_H2P, N1, N2);
    k_att2  <<<2048, 256, 0, stream>>>(x1, x2, N1, N2, ws);
    k_comb  <<<1,    512, 0, stream>>>(ws);
    k_ntn   <<<512,  256, 0, stream>>>(W, ws);
    k_final <<<1,    256, 0, stream>>>(V, b, P0, P1, P2, P3, ws, out);
}